// Round 2
// baseline (270.744 us; speedup 1.0000x reference)
//
#include <hip/hip_runtime.h>
#include <math.h>

#define NB    16        // batch
#define NC    25        // channels
#define HW    65536     // 256*256
#define CHW   (NC * HW)
#define EPSF  1e-8f
#define TPB   256       // 4 waves
#define BPI   64        // blocks per image; slab = 1024 px
#define SLAB  1024
#define GR    5         // channels per register-staged group
#define NBLK  (NB * BPI) // 1024 blocks

union F4 { float4 v; float a[4]; };

__device__ __forceinline__ float wave_reduce(float v) {
#pragma unroll
    for (int o = 32; o > 0; o >>= 1) v += __shfl_down(v, o, 64);
    return v;
}

// R9: no LDS staging at all. R7/R8 post-mortem: compiler emits s_waitcnt
// vmcnt(0) before ANY read of lds[] that may alias a global_load_lds write,
// so the "pipeline" drained every stage; LDS size also pinned 1 block/CU
// (4 waves). In-flight bytes alternated 40KB->0 -> ~2.6 TB/s latency-bound
// plateau (L3-warm dispatches at 75us with hbm_bytes~70KB prove latency,
// not BW, is the wall). Fix: VGPR A/B double-buffer (10 x float4 per group)
// -- the compiler's per-register vmcnt tracking gives counted waits for
// free -- plus 3-4 blocks/CU of TLP (no LDS, ~110 VGPR). 12-16 waves/CU
// x 10-20KB outstanding each >> the ~10KB/CU Little's-law target.
// Finalize is merged in via atomic ticket (last block computes out[]),
// dropping the yolo_fin graph node.
__global__ __launch_bounds__(TPB) void yolo_main(const float* __restrict__ outputs,
                                                 const float* __restrict__ labels,
                                                 float* __restrict__ acc,
                                                 unsigned* __restrict__ ticket,
                                                 float* __restrict__ out) {
    const int b    = blockIdx.x / BPI;
    const int slab = blockIdx.x % BPI;
    const int wv   = threadIdx.x >> 6;
    const int lane = threadIdx.x & 63;
    const size_t base = (size_t)b * CHW + (size_t)slab * SLAB + (size_t)threadIdx.x * 4;
    const float* og = outputs + base;   // this thread's 4 px, channel 0
    const float* lg = labels  + base;

    float y0[4], vmax[4], vout[4];
    float obj = 0.f, szs = 0.f, offs = 0.f, cls = 0.f;
    float tp = 0.f, fp = 0.f, fn = 0.f;
#pragma unroll
    for (int i = 0; i < 4; ++i) { vmax[i] = -1.0f; vout[i] = 0.0f; }

    F4 oA[GR], lA[GR], oB[GR], lB[GR];

    // ---- issue group 0 (ch 0..4) -> A, group 1 (ch 5..9) -> B : 20 loads in flight
#pragma unroll
    for (int ci = 0; ci < GR; ++ci) {
        oA[ci].v = *(const float4*)(og + (size_t)ci * HW);
        lA[ci].v = *(const float4*)(lg + (size_t)ci * HW);
    }
#pragma unroll
    for (int ci = 0; ci < GR; ++ci) {
        oB[ci].v = *(const float4*)(og + (size_t)(GR + ci) * HW);
        lB[ci].v = *(const float4*)(lg + (size_t)(GR + ci) * HW);
    }

    // ---- consume group 0 (A): BCE + F1 + size/offset L1  (waits A only)
#pragma unroll
    for (int i = 0; i < 4; ++i) {
        float xv = oA[0].a[i], yv = lA[0].a[i];
        float xc = fminf(fmaxf(xv,        EPSF), 1.0f - EPSF);
        float x1 = fminf(fmaxf(1.0f - xv, EPSF), 1.0f - EPSF);
        obj += -yv * (1.0f - xc) * __logf(xc)
               - (1.0f - yv) * (1.0f - x1) * __logf(x1);
        float p  = (xv > 0.5f) ? 1.f : 0.f;
        float yt = (yv > 0.5f) ? 1.f : 0.f;
        tp += p * yt;
        fp += p * (1.f - yt);
        fn += (1.f - p) * yt;
        y0[i] = yv;
    }
#pragma unroll
    for (int ci = 1; ci <= 4; ++ci) {
        float s = 0.f;
#pragma unroll
        for (int i = 0; i < 4; ++i) s += y0[i] * fabsf(oA[ci].a[i] - lA[ci].a[i]);
        if (ci <= 2) szs += s; else offs += s;
    }

    // argmax(labels ch5..24) carrying outputs; ascending order + strict '>'
    // = first-index tie-break. Consume order g1,g2,g3,g4 ascending.
    auto consume_cls = [&](F4* o, F4* l) {
#pragma unroll
        for (int ci = 0; ci < GR; ++ci) {
#pragma unroll
            for (int i = 0; i < 4; ++i) {
                if (l[ci].a[i] > vmax[i]) { vmax[i] = l[ci].a[i]; vout[i] = o[ci].a[i]; }
            }
        }
    };
    auto load_grp = [&](int g, F4* o, F4* l) {
#pragma unroll
        for (int ci = 0; ci < GR; ++ci) {
            o[ci].v = *(const float4*)(og + (size_t)(g * GR + ci) * HW);
            l[ci].v = *(const float4*)(lg + (size_t)(g * GR + ci) * HW);
        }
    };

    load_grp(2, oA, lA);      // A free after group-0 consume
    consume_cls(oB, lB);      // g1 (waits B's 10 only; g2 still flying)
    load_grp(3, oB, lB);
    consume_cls(oA, lA);      // g2
    load_grp(4, oA, lA);
    consume_cls(oB, lB);      // g3
    consume_cls(oA, lA);      // g4

#pragma unroll
    for (int i = 0; i < 4; ++i) cls += y0[i] * (-vout[i]);

    // ---- block reduction: 7 values
    obj  = wave_reduce(obj);
    szs  = wave_reduce(szs);
    offs = wave_reduce(offs);
    cls  = wave_reduce(cls);
    tp   = wave_reduce(tp);
    fp   = wave_reduce(fp);
    fn   = wave_reduce(fn);

    __shared__ float sm[TPB / 64][7];
    if (lane == 0) {
        sm[wv][0] = obj;  sm[wv][1] = szs; sm[wv][2] = offs;
        sm[wv][3] = cls;  sm[wv][4] = tp;  sm[wv][5] = fp;  sm[wv][6] = fn;
    }
    __syncthreads();
    if (threadIdx.x < 7) {
        float s = 0.f;
#pragma unroll
        for (int w = 0; w < TPB / 64; ++w) s += sm[w][threadIdx.x];
        if (threadIdx.x < 4) atomicAdd(&acc[threadIdx.x], s);
        else                 atomicAdd(&acc[4 + 3 * b + (threadIdx.x - 4)], s);
    }
    __syncthreads();          // all 7 atomics issued+drained (barrier waits vmcnt)

    // ---- ticket: last block finalizes (replaces yolo_fin launch)
    __shared__ unsigned oldt;
    if (threadIdx.x == 0) {
        __threadfence();      // release our acc adds before the ticket
        oldt = atomicAdd(ticket, 1u);
    }
    __syncthreads();
    if (oldt == NBLK - 1) {
        __shared__ float fin[4 + 3 * NB];
        if (threadIdx.x < 4 + 3 * NB) {
            // coherent RMW-read: sees every block's released adds
            fin[threadIdx.x] = atomicAdd(&acc[threadIdx.x], 0.0f);
        }
        __syncthreads();
        if (threadIdx.x == 0) {
            float objT = fin[0];
            float szT  = 0.1f * fin[1];
            float offT = 0.1f * fin[2];
            float clsT = fin[3];
            float f1 = 0.f;
            for (int bb = 0; bb < NB; ++bb) {
                float tpv = fin[4 + 3 * bb], fpv = fin[5 + 3 * bb], fnv = fin[6 + 3 * bb];
                float den = 2.f * tpv + fpv + fnv;
                f1 += (den > 0.f) ? (2.f * tpv) / fmaxf(den, 1.f) : 0.f;
            }
            f1 *= (1.0f / NB);
            out[0] = objT + szT + offT + clsT;
            out[1] = f1;
            out[2] = objT;
            out[3] = szT;
            out[4] = offT;
            out[5] = clsT;
        }
    }
}

extern "C" void kernel_launch(void* const* d_in, const int* in_sizes, int n_in,
                              void* d_out, int out_size, void* d_ws, size_t ws_size,
                              hipStream_t stream) {
    const float* outputs = (const float*)d_in[0];
    const float* labels  = (const float*)d_in[1];
    float* acc = (float*)d_ws;                    // [0..3] losses, [4+3b..] tp,fp,fn
    unsigned* ticket = (unsigned*)((float*)d_ws + 4 + 3 * NB);

    hipMemsetAsync(d_ws, 0, (4 + 3 * NB + 1) * sizeof(float), stream);
    yolo_main<<<NBLK, TPB, 0, stream>>>(outputs, labels, acc, ticket, (float*)d_out);
}